// Round 1
// baseline (147.900 us; speedup 1.0000x reference)
//
#include <hip/hip_runtime.h>

#define EPS 1.1920928955078125e-07f

// Problem constants (hard-coded so loops fully unroll)
#define BB 32
#define TT 256000
#define CHUNKS 50                 // chunks per batch element
#define T4 (TT / 4)               // 64000 float4 per signal
#define CHUNK (T4 / CHUNKS)       // 1280 float4 per block
#define ITERS (CHUNK / 256)       // 5 iterations per thread
#define NBLK (BB * CHUNKS)        // 1600 partial blocks

// 12 per-batch statistics (raw sums; zero-meaning folded in at finalize):
// [0] sum p0   [1] sum p1   [2] sum t0   [3] sum t1
// [4] sum p0^2 [5] sum p1^2 [6] sum t0^2 [7] sum t1^2
// [8] sum p0*t0 [9] sum p0*t1 [10] sum p1*t0 [11] sum p1*t1

// launch_bounds(256, 6): VGPR cap ~85 so the depth-2 pipeline's 48-VGPR
// load buffer fits without spilling; 6 waves/EU floor keeps >=24 waves/CU,
// matching the grid's 6.25 blocks/CU average.
__global__ __launch_bounds__(256, 6) void pit_partials(
    const float* __restrict__ preds, const float* __restrict__ targets,
    float* __restrict__ ws)
{
    const int b = blockIdx.x / CHUNKS;
    const int c = blockIdx.x % CHUNKS;

    const float4* p0 = (const float4*)(preds   + (size_t)(b * 2 + 0) * TT);
    const float4* p1 = (const float4*)(preds   + (size_t)(b * 2 + 1) * TT);
    const float4* t0 = (const float4*)(targets + (size_t)(b * 2 + 0) * TT);
    const float4* t1 = (const float4*)(targets + (size_t)(b * 2 + 1) * TT);

    const int base = c * CHUNK + (int)threadIdx.x;

    // Depth-2 software pipeline: 3 rotating register buffers of 4 float4
    // each => up to 12 global_load_dwordx4 in flight per thread, so the
    // per-iteration load->waitcnt(0)->compute serialization (the 40-VGPR
    // schedule of the previous version) is broken.
    float4 ba0[3], ba1[3], bb0[3], bb1[3];
    {
        const int i0 = base;
        ba0[0] = p0[i0]; ba1[0] = p1[i0]; bb0[0] = t0[i0]; bb1[0] = t1[i0];
        const int i1 = base + 256;
        ba0[1] = p0[i1]; ba1[1] = p1[i1]; bb0[1] = t0[i1]; bb1[1] = t1[i1];
    }

    float acc[12];
#pragma unroll
    for (int k = 0; k < 12; ++k) acc[k] = 0.f;

#pragma unroll
    for (int it = 0; it < ITERS; ++it) {
        const int cur = it % 3;            // compile-time after unroll
        if (it + 2 < ITERS) {
            const int nb = (it + 2) % 3;   // compile-time after unroll
            const int i = base + (it + 2) * 256;
            ba0[nb] = p0[i]; ba1[nb] = p1[i]; bb0[nb] = t0[i]; bb1[nb] = t1[i];
        }
        float4 a0 = ba0[cur];
        float4 a1 = ba1[cur];
        float4 b0 = bb0[cur];
        float4 b1 = bb1[cur];
#pragma unroll
        for (int e = 0; e < 4; ++e) {
            float u0 = (&a0.x)[e], u1 = (&a1.x)[e];
            float v0 = (&b0.x)[e], v1 = (&b1.x)[e];
            acc[0]  += u0;       acc[1]  += u1;
            acc[2]  += v0;       acc[3]  += v1;
            acc[4]  += u0 * u0;  acc[5]  += u1 * u1;
            acc[6]  += v0 * v0;  acc[7]  += v1 * v1;
            acc[8]  += u0 * v0;  acc[9]  += u0 * v1;
            acc[10] += u1 * v0;  acc[11] += u1 * v1;
        }
    }

    // wave(64)-level shuffle reduction for all 12 stats
    const int lane = threadIdx.x & 63;
    const int wave = threadIdx.x >> 6;
#pragma unroll
    for (int k = 0; k < 12; ++k) {
        float v = acc[k];
        for (int off = 32; off > 0; off >>= 1) v += __shfl_down(v, off);
        acc[k] = v;   // valid in lane 0 of each wave
    }

    __shared__ float lds[4][12];
    if (lane == 0) {
#pragma unroll
        for (int k = 0; k < 12; ++k) lds[wave][k] = acc[k];
    }
    __syncthreads();

    // threads 0..11: sum the 4 wave-partials, plain store (no atomics, no memset needed)
    if (threadIdx.x < 12) {
        float v = lds[0][threadIdx.x] + lds[1][threadIdx.x]
                + lds[2][threadIdx.x] + lds[3][threadIdx.x];
        ws[(size_t)blockIdx.x * 12 + threadIdx.x] = v;
    }
}

// Reduce NBLK x 12 partials -> B x 12 stats -> SI-SNR -> PIT -> scalar loss
__global__ __launch_bounds__(256) void pit_final(
    const float* __restrict__ ws, float* __restrict__ out)
{
    __shared__ float sums[BB * 12];   // 384 stat slots
    __shared__ float bests[BB];

    // each thread owns 1-2 (b,k) stat slots; sums 50 chunk-partials each
    for (int s = threadIdx.x; s < BB * 12; s += 256) {
        const int b = s / 12;
        const int k = s % 12;
        float v = 0.f;
        const float* base = ws + (size_t)(b * CHUNKS) * 12 + k;
#pragma unroll 10
        for (int c = 0; c < CHUNKS; ++c) v += base[(size_t)c * 12];
        sums[s] = v;
    }
    __syncthreads();

    if (threadIdx.x < BB) {
        const float* w = sums + threadIdx.x * 12;
        const float invT = 1.0f / (float)TT;
        float pp0 = w[4] - w[0] * w[0] * invT;
        float pp1 = w[5] - w[1] * w[1] * invT;
        float tt0 = w[6] - w[2] * w[2] * invT;
        float tt1 = w[7] - w[3] * w[3] * invT;
        float d00 = w[8]  - w[0] * w[2] * invT;
        float d01 = w[9]  - w[0] * w[3] * invT;
        float d10 = w[10] - w[1] * w[2] * invT;
        float d11 = w[11] - w[1] * w[3] * invT;

        auto sisnr = [](float dot, float pp, float tt) -> float {
            float alpha = dot / (tt + EPS);
            float st    = alpha * alpha * tt;
            float noise = pp - 2.0f * alpha * dot + st;
            return 10.0f * log10f((st + EPS) / (noise + EPS));
        };
        float s00 = sisnr(d00, pp0, tt0);
        float s01 = sisnr(d01, pp0, tt1);
        float s10 = sisnr(d10, pp1, tt0);
        float s11 = sisnr(d11, pp1, tt1);

        float perm0 = 0.5f * (s00 + s11);   // identity permutation
        float perm1 = 0.5f * (s01 + s10);   // swapped permutation
        bests[threadIdx.x] = fmaxf(perm0, perm1);
    }
    __syncthreads();

    if (threadIdx.x == 0) {
        float acc = 0.f;
#pragma unroll
        for (int b = 0; b < BB; ++b) acc += bests[b];
        out[0] = -acc / (float)BB;
    }
}

extern "C" void kernel_launch(void* const* d_in, const int* in_sizes, int n_in,
                              void* d_out, int out_size, void* d_ws, size_t ws_size,
                              hipStream_t stream)
{
    const float* preds   = (const float*)d_in[0];
    const float* targets = (const float*)d_in[1];
    float* out = (float*)d_out;
    float* ws  = (float*)d_ws;   // NBLK*12 floats = 76.8 KB of scratch

    pit_partials<<<dim3(NBLK), dim3(256), 0, stream>>>(preds, targets, ws);
    pit_final<<<dim3(1), dim3(256), 0, stream>>>(ws, out);
}

// Round 3
// 145.886 us; speedup vs baseline: 1.0138x; 1.0138x over previous
//
#include <hip/hip_runtime.h>

#define EPS 1.1920928955078125e-07f

// Problem constants (hard-coded so loops fully unroll)
#define BB 32
#define TT 256000
#define T4 (TT / 4)               // 64000 float4 per signal
#define CHUNK 512                 // float4 per stream per block (32 KB LDS tile)
#define CHUNKS (T4 / CHUNK)       // 125 chunks per batch element
#define NBLK (BB * CHUNKS)        // 4000 partial blocks
#define ITERS (CHUNK / 256)       // 2 float4 per thread per stream
#define SEGS (CHUNK / 64)         // 8 global_load_lds (1024 B each) per wave

// ws layout: NBLK x 12 chunk partials (float). 192,000 B of scratch.
// Nothing in ws is read before being written in the same dispatch sequence,
// so workspace poisoning between calls is harmless.
//
// 12 per-batch statistics (raw sums; zero-meaning folded in at finalize):
// [0] sum p0   [1] sum p1   [2] sum t0   [3] sum t1
// [4] sum p0^2 [5] sum p1^2 [6] sum t0^2 [7] sum t1^2
// [8] sum p0*t0 [9] sum p0*t1 [10] sum p1*t0 [11] sum p1*t1

// Async global->LDS DMA: no VGPR round-trip, no per-thread load serialization.
// Each call moves 64 lanes x 16 B = 1024 B. LDS dest is wave-uniform base +
// lane*16 (linear); global src is per-lane. (m97 pattern, width=16.)
__device__ __forceinline__ void gload16(const float4* g, float4* l)
{
    __builtin_amdgcn_global_load_lds(
        (const __attribute__((address_space(1))) void*)(const void*)g,
        (__attribute__((address_space(3))) void*)(void*)l,
        16, 0, 0);
}

__global__ __launch_bounds__(256, 8) void pit_partials(
    const float* __restrict__ preds, const float* __restrict__ targets,
    float* __restrict__ ws)
{
    __shared__ float4 lds4[4 * CHUNK];   // 32 KB: 5 blocks/CU -> 160 KB DMA in flight/CU
    float* f = (float*)lds4;

    const int tid  = threadIdx.x;
    const int lane = tid & 63;
    const int wave = tid >> 6;

    const int b = blockIdx.x / CHUNKS;
    const int c = blockIdx.x % CHUNKS;

    // one stream per wave: 0=p0 1=p1 2=t0 3=t1
    const float* sb =
        (wave == 0) ? preds   + (size_t)(b * 2 + 0) * TT :
        (wave == 1) ? preds   + (size_t)(b * 2 + 1) * TT :
        (wave == 2) ? targets + (size_t)(b * 2 + 0) * TT :
                      targets + (size_t)(b * 2 + 1) * TT;

    const float4* g = (const float4*)sb + (size_t)c * CHUNK + lane;
    float4* l = &lds4[wave * CHUNK];
#pragma unroll
    for (int k = 0; k < SEGS; ++k)
        gload16(g + k * 64, l + k * 64);

    // compiler emits s_waitcnt vmcnt(0) before s_barrier: all 4 streams staged
    __syncthreads();

    float acc[12];
#pragma unroll
    for (int k = 0; k < 12; ++k) acc[k] = 0.f;

#pragma unroll
    for (int it = 0; it < ITERS; ++it) {
        const int i = it * 256 + tid;
        float4 a0 = lds4[0 * CHUNK + i];   // lane-contiguous ds_read_b128:
        float4 a1 = lds4[1 * CHUNK + i];   // 2 lanes/bank aliasing = free
        float4 b0 = lds4[2 * CHUNK + i];
        float4 b1 = lds4[3 * CHUNK + i];
#pragma unroll
        for (int e = 0; e < 4; ++e) {
            float u0 = (&a0.x)[e], u1 = (&a1.x)[e];
            float v0 = (&b0.x)[e], v1 = (&b1.x)[e];
            acc[0]  += u0;       acc[1]  += u1;
            acc[2]  += v0;       acc[3]  += v1;
            acc[4]  += u0 * u0;  acc[5]  += u1 * u1;
            acc[6]  += v0 * v0;  acc[7]  += v1 * v1;
            acc[8]  += u0 * v0;  acc[9]  += u0 * v1;
            acc[10] += u1 * v0;  acc[11] += u1 * v1;
        }
    }

    // wave(64)-level shuffle reduction for all 12 stats
#pragma unroll
    for (int k = 0; k < 12; ++k) {
        float v = acc[k];
        for (int off = 32; off > 0; off >>= 1) v += __shfl_down(v, off);
        acc[k] = v;   // valid in lane 0 of each wave
    }

    __syncthreads();   // staging reads done; safe to overwrite LDS
    if (lane == 0) {
#pragma unroll
        for (int k = 0; k < 12; ++k) f[wave * 12 + k] = acc[k];
    }
    __syncthreads();

    // threads 0..11: sum the 4 wave-partials, plain store (no atomics)
    if (tid < 12) {
        float v = f[0 + tid] + f[12 + tid] + f[24 + tid] + f[36 + tid];
        ws[(size_t)blockIdx.x * 12 + tid] = v;
    }
}

// Reduce NBLK x 12 partials -> B x 12 stats -> SI-SNR -> PIT -> scalar loss
__global__ __launch_bounds__(256) void pit_final(
    const float* __restrict__ ws, float* __restrict__ out)
{
    __shared__ float sums[BB * 12];   // 384 stat slots
    __shared__ float bests[BB];

    // each thread owns 1-2 (b,k) stat slots; sums 125 chunk-partials each
    for (int s = threadIdx.x; s < BB * 12; s += 256) {
        const int b = s / 12;
        const int k = s % 12;
        float v = 0.f;
        const float* base = ws + (size_t)(b * CHUNKS) * 12 + k;
#pragma unroll 25
        for (int c = 0; c < CHUNKS; ++c) v += base[(size_t)c * 12];
        sums[s] = v;
    }
    __syncthreads();

    if (threadIdx.x < BB) {
        const float* w = sums + threadIdx.x * 12;
        const float invT = 1.0f / (float)TT;
        float pp0 = w[4] - w[0] * w[0] * invT;
        float pp1 = w[5] - w[1] * w[1] * invT;
        float tt0 = w[6] - w[2] * w[2] * invT;
        float tt1 = w[7] - w[3] * w[3] * invT;
        float d00 = w[8]  - w[0] * w[2] * invT;
        float d01 = w[9]  - w[0] * w[3] * invT;
        float d10 = w[10] - w[1] * w[2] * invT;
        float d11 = w[11] - w[1] * w[3] * invT;

        auto sisnr = [](float dot, float pp, float tt) -> float {
            float alpha = dot / (tt + EPS);
            float st    = alpha * alpha * tt;
            float noise = pp - 2.0f * alpha * dot + st;
            return 10.0f * log10f((st + EPS) / (noise + EPS));
        };
        float s00 = sisnr(d00, pp0, tt0);
        float s01 = sisnr(d01, pp0, tt1);
        float s10 = sisnr(d10, pp1, tt0);
        float s11 = sisnr(d11, pp1, tt1);

        float perm0 = 0.5f * (s00 + s11);   // identity permutation
        float perm1 = 0.5f * (s01 + s10);   // swapped permutation
        bests[threadIdx.x] = fmaxf(perm0, perm1);
    }
    __syncthreads();

    if (threadIdx.x == 0) {
        float acc = 0.f;
#pragma unroll
        for (int b = 0; b < BB; ++b) acc += bests[b];
        out[0] = -acc / (float)BB;
    }
}

extern "C" void kernel_launch(void* const* d_in, const int* in_sizes, int n_in,
                              void* d_out, int out_size, void* d_ws, size_t ws_size,
                              hipStream_t stream)
{
    const float* preds   = (const float*)d_in[0];
    const float* targets = (const float*)d_in[1];
    float* out = (float*)d_out;
    float* ws  = (float*)d_ws;   // NBLK*12 floats = 192,000 B of scratch

    pit_partials<<<dim3(NBLK), dim3(256), 0, stream>>>(preds, targets, ws);
    pit_final<<<dim3(1), dim3(256), 0, stream>>>(ws, out);
}